// Round 17
// baseline (175.285 us; speedup 1.0000x reference)
//
#include <hip/hip_runtime.h>

// LIF neuron scan: v = v*0.5 + x[t]; s = (v - 0.5 > 0); v -= s*0.5
// Round 16 -> 17: SELF-MEASURING A/B ON THE READ SIDE.
// Inference from R14 vs R16 (two radically different K2 shapes within 2us):
// K2 ~ 30us (write floor), so K1 ~ 67us = 210MB read at 3.2 TB/s = half the
// copy ceiling. Theory: 12 single-wave blocks/CU each go dark for the
// 2000-4000cyc serial walk after issuing 13 loads -> average in-flight read
// bytes/CU sag below the ~9.2KB Little's-law requirement.
// K1_b: LDS slab 5 f4/row (5.1KB -> 24+ waves/CU @ launch_bounds(64,6)),
// 100 steps in 5 sub-passes with 1-sub-pass register lookahead -> every wave
// holds 5KB of loads in flight at ALL times (~120KB/CU).
// Launch order: K1_a (R16 verbatim) -> K1_b (writes IDENTICAL bits, so
// correctness-safe) -> K2 (R16 verbatim). Since R16 = K1_a + K2 = 97.6us,
// dur - 97.6 = K1_b's exact duration. Decision: K1_b <= 45 -> ship K1_b+K2
// next round; K1_b >= 55 -> reads platform-capped, ~90us is the floor.

#define T_STEPS 100
#define T_VEC   25      // f4 per row in global
#define ROWS    64      // rows per block == blockDim.x (one wave)
#define CA      12      // K1_a pass-A f4 chunks
#define CB      13      // K1_a pass-B f4 chunks
#define LSTRIDE 13      // K1_a tile row stride in f4
#define W5      5       // K1_b sub-pass width in f4 (odd -> gcd(5,8)=1, no conflicts)
#define DECAY   0.5f
#define VTH     0.5f

typedef float vfloat4 __attribute__((ext_vector_type(4)));

// ---------------- K1_a: R16's lif_walk, verbatim ----------------------------
__global__ __launch_bounds__(64, 3) void lif_walk(const float* __restrict__ x,
                                                  uint4* __restrict__ bitsg,
                                                  int n_rows) {
    __shared__ vfloat4 tile[ROWS * LSTRIDE];   // 13,312 B

    const int lane = threadIdx.x;
    const int row0 = blockIdx.x * ROWS;
    const int gf0 = row0 * T_VEC;
    const int total_f4 = n_rows * T_VEC;

    const vfloat4* __restrict__ xb = reinterpret_cast<const vfloat4*>(x);
    const vfloat4 vzero = {0.0f, 0.0f, 0.0f, 0.0f};

    {
        vfloat4 st[CA];
        #pragma unroll
        for (int k = 0; k < CA; ++k) {
            int f = k * 64 + lane;
            int r = f / CA, c = f % CA;
            int g = gf0 + r * T_VEC + c;
            st[k] = (g < total_f4) ? xb[g] : vzero;
        }
        #pragma unroll
        for (int k = 0; k < CA; ++k) {
            int f = k * 64 + lane;
            int r = f / CA, c = f % CA;
            tile[r * LSTRIDE + c] = st[k];
        }
    }
    __syncthreads();

    vfloat4 sb[CB];
    #pragma unroll
    for (int k = 0; k < CB; ++k) {
        int f = k * 64 + lane;
        int r = f / CB, c = f % CB;
        int g = gf0 + r * T_VEC + CA + c;
        sb[k] = (g < total_f4) ? xb[g] : vzero;
    }
    __builtin_amdgcn_sched_barrier(0);

    unsigned int pk0 = 0, pk1 = 0, pk2 = 0, pk3 = 0;
    float v = 0.0f;
    #pragma unroll
    for (int c = 0; c < CA; ++c) {
        vfloat4 xs = tile[lane * LSTRIDE + c];
        #pragma unroll
        for (int k = 0; k < 4; ++k) {
            v = v * DECAY + xs[k];
            bool s = (v - VTH > 0.0f);
            v -= s ? VTH : 0.0f;
            unsigned int bit = s ? 1u : 0u;
            const int b = c * 4 + k;
            if (b < 32) pk0 |= bit << b;
            else        pk1 |= bit << (b - 32);
        }
    }
    __syncthreads();

    #pragma unroll
    for (int k = 0; k < CB; ++k) {
        int f = k * 64 + lane;
        int r = f / CB, c = f % CB;
        tile[r * LSTRIDE + c] = sb[k];
    }
    __syncthreads();

    #pragma unroll
    for (int c = 0; c < CB; ++c) {
        vfloat4 xs = tile[lane * LSTRIDE + c];
        #pragma unroll
        for (int k = 0; k < 4; ++k) {
            v = v * DECAY + xs[k];
            bool s = (v - VTH > 0.0f);
            v -= s ? VTH : 0.0f;
            unsigned int bit = s ? 1u : 0u;
            const int b = 48 + c * 4 + k;
            if (b < 64)      pk1 |= bit << (b - 32);
            else if (b < 96) pk2 |= bit << (b - 64);
            else             pk3 |= bit << (b - 96);
        }
    }

    if (row0 + lane < n_rows) {
        uint4 w; w.x = pk0; w.y = pk1; w.z = pk2; w.w = pk3;
        bitsg[row0 + lane] = w;
    }
}

// ---------------- K1_b: high-occupancy pipelined walker ---------------------
// 5.1KB slab -> 24+ waves/CU; 5 sub-passes of 20 steps with 1-sub-pass reg
// lookahead; sched_barrier(0) fences pin compiler order at slab phase
// boundaries (HW order = wave-private in-order DS pipe); no vmcnt drains.
__global__ __launch_bounds__(64, 6) void lif_walk_b(const float* __restrict__ x,
                                                    uint4* __restrict__ bitsg,
                                                    int n_rows) {
    __shared__ vfloat4 slab[ROWS * W5];   // 5,120 B

    const int lane = threadIdx.x;
    const int row0 = blockIdx.x * ROWS;
    const int gf0 = row0 * T_VEC;
    const int total_f4 = n_rows * T_VEC;

    const vfloat4* __restrict__ xb = reinterpret_cast<const vfloat4*>(x);
    const vfloat4 vz = {0.0f, 0.0f, 0.0f, 0.0f};

    vfloat4 ld[2][W5];

    // Prologue: sub-pass 0 loads into ld[0]
    #pragma unroll
    for (int k = 0; k < W5; ++k) {
        int f = k * 64 + lane;               // 0..319
        int r = f / W5, c = f % W5;
        int g = gf0 + r * T_VEC + c;
        ld[0][k] = (g < total_f4) ? xb[g] : vz;
    }

    unsigned int pk0 = 0, pk1 = 0, pk2 = 0, pk3 = 0;
    float v = 0.0f;

    #pragma unroll
    for (int s = 0; s < 5; ++s) {
        const int cur = s & 1, nxt = cur ^ 1;

        // Issue next sub-pass loads first (kept in flight through the walk).
        if (s < 4) {
            #pragma unroll
            for (int k = 0; k < W5; ++k) {
                int f = k * 64 + lane;
                int r = f / W5, c = f % W5;
                int g = gf0 + r * T_VEC + (s + 1) * W5 + c;
                ld[nxt][k] = (g < total_f4) ? xb[g] : vz;
            }
        }
        __builtin_amdgcn_sched_barrier(0);

        // Stage current sub-pass (compiler inserts counted vmcnt for ld[cur]
        // only; ld[nxt] stays in flight).
        #pragma unroll
        for (int k = 0; k < W5; ++k) {
            int f = k * 64 + lane;
            int r = f / W5, c = f % W5;
            slab[r * W5 + c] = ld[cur][k];
        }
        __builtin_amdgcn_sched_barrier(0);   // pin: writes before reads

        // Walk own row's 20 steps from the slab.
        #pragma unroll
        for (int c = 0; c < W5; ++c) {
            vfloat4 xs = slab[lane * W5 + c];
            #pragma unroll
            for (int k = 0; k < 4; ++k) {
                // v*0.5 exact (pow2); conditional -0.5 exact -> bitwise == ref.
                v = v * DECAY + xs[k];
                bool sp = (v - VTH > 0.0f);
                v -= sp ? VTH : 0.0f;
                unsigned int bit = sp ? 1u : 0u;
                const int b = s * 20 + c * 4 + k;   // compile-time 0..99
                if      (b < 32) pk0 |= bit << b;
                else if (b < 64) pk1 |= bit << (b - 32);
                else if (b < 96) pk2 |= bit << (b - 64);
                else             pk3 |= bit << (b - 96);
            }
        }
        __builtin_amdgcn_sched_barrier(0);   // pin: reads before next writes
    }

    if (row0 + lane < n_rows) {
        uint4 w; w.x = pk0; w.y = pk1; w.z = pk2; w.w = pk3;
        bitsg[row0 + lane] = w;
    }
}

// ---------------- K2: fill-shaped expander (R16 verbatim) -------------------
__global__ __launch_bounds__(256) void lif_expand(const unsigned int* __restrict__ bw,
                                                  vfloat4* __restrict__ ob,
                                                  int total_f4) {
    int f = blockIdx.x * 256 + threadIdx.x;
    if (f >= total_f4) return;
    int r  = f / T_VEC;
    int c4 = f % T_VEC;
    unsigned int word = bw[r * 4 + (c4 >> 3)];
    unsigned int nib = (word >> ((c4 & 7) * 4)) & 0xFu;
    vfloat4 s;
    s.x = (nib & 1u) ? 1.0f : 0.0f;
    s.y = (nib & 2u) ? 1.0f : 0.0f;
    s.z = (nib & 4u) ? 1.0f : 0.0f;
    s.w = (nib & 8u) ? 1.0f : 0.0f;
    ob[f] = s;
}

// ---------------- Fallback: R13 single kernel (ws too small) ----------------
__global__ __launch_bounds__(64, 3) void lif_kernel(const float* __restrict__ x,
                                                    float* __restrict__ out,
                                                    int n_rows) {
    __shared__ vfloat4 tile[ROWS * LSTRIDE];
    __shared__ unsigned int bits[ROWS * 4];

    const int lane = threadIdx.x;
    const int row0 = blockIdx.x * ROWS;
    const int gf0 = row0 * T_VEC;
    const int total_f4 = n_rows * T_VEC;

    const vfloat4* __restrict__ xb = reinterpret_cast<const vfloat4*>(x);
    const vfloat4 vzero = {0.0f, 0.0f, 0.0f, 0.0f};

    {
        vfloat4 st[CA];
        #pragma unroll
        for (int k = 0; k < CA; ++k) {
            int f = k * 64 + lane;
            int r = f / CA, c = f % CA;
            int g = gf0 + r * T_VEC + c;
            st[k] = (g < total_f4) ? xb[g] : vzero;
        }
        #pragma unroll
        for (int k = 0; k < CA; ++k) {
            int f = k * 64 + lane;
            int r = f / CA, c = f % CA;
            tile[r * LSTRIDE + c] = st[k];
        }
    }
    __syncthreads();

    vfloat4 sb[CB];
    #pragma unroll
    for (int k = 0; k < CB; ++k) {
        int f = k * 64 + lane;
        int r = f / CB, c = f % CB;
        int g = gf0 + r * T_VEC + CA + c;
        sb[k] = (g < total_f4) ? xb[g] : vzero;
    }
    __builtin_amdgcn_sched_barrier(0);

    unsigned int pk0 = 0, pk1 = 0, pk2 = 0, pk3 = 0;
    float v = 0.0f;
    #pragma unroll
    for (int c = 0; c < CA; ++c) {
        vfloat4 xs = tile[lane * LSTRIDE + c];
        #pragma unroll
        for (int k = 0; k < 4; ++k) {
            v = v * DECAY + xs[k];
            bool s = (v - VTH > 0.0f);
            v -= s ? VTH : 0.0f;
            unsigned int bit = s ? 1u : 0u;
            const int b = c * 4 + k;
            if (b < 32) pk0 |= bit << b;
            else        pk1 |= bit << (b - 32);
        }
    }
    __syncthreads();

    #pragma unroll
    for (int k = 0; k < CB; ++k) {
        int f = k * 64 + lane;
        int r = f / CB, c = f % CB;
        tile[r * LSTRIDE + c] = sb[k];
    }
    __syncthreads();

    #pragma unroll
    for (int c = 0; c < CB; ++c) {
        vfloat4 xs = tile[lane * LSTRIDE + c];
        #pragma unroll
        for (int k = 0; k < 4; ++k) {
            v = v * DECAY + xs[k];
            bool s = (v - VTH > 0.0f);
            v -= s ? VTH : 0.0f;
            unsigned int bit = s ? 1u : 0u;
            const int b = 48 + c * 4 + k;
            if (b < 64)      pk1 |= bit << (b - 32);
            else if (b < 96) pk2 |= bit << (b - 64);
            else             pk3 |= bit << (b - 96);
        }
    }

    {
        uint4 w; w.x = pk0; w.y = pk1; w.z = pk2; w.w = pk3;
        reinterpret_cast<uint4*>(bits)[lane] = w;
    }
    __syncthreads();

    vfloat4* __restrict__ ob = reinterpret_cast<vfloat4*>(out);
    #pragma unroll
    for (int i = 0; i < T_VEC; ++i) {
        int f = i * 64 + lane;
        int g = gf0 + f;
        if (g < total_f4) {
            int r  = f / T_VEC;
            int c4 = f % T_VEC;
            unsigned int word = bits[r * 4 + (c4 >> 3)];
            unsigned int nib = (word >> ((c4 & 7) * 4)) & 0xFu;
            vfloat4 s;
            s.x = (nib & 1u) ? 1.0f : 0.0f;
            s.y = (nib & 2u) ? 1.0f : 0.0f;
            s.z = (nib & 4u) ? 1.0f : 0.0f;
            s.w = (nib & 8u) ? 1.0f : 0.0f;
            ob[g] = s;
        }
    }
}

extern "C" void kernel_launch(void* const* d_in, const int* in_sizes, int n_in,
                              void* d_out, int out_size, void* d_ws, size_t ws_size,
                              hipStream_t stream) {
    const float* x = (const float*)d_in[0];
    float* out = (float*)d_out;

    int n_rows = in_sizes[0] / T_STEPS;              // 32 * 16384 = 524288
    int total_f4 = n_rows * T_VEC;                   // 13,107,200
    int grid1 = (n_rows + ROWS - 1) / ROWS;          // 8192

    size_t need = (size_t)n_rows * 16;               // 8.4 MB of packed bits
    if (ws_size >= need) {
        int grid2 = (total_f4 + 255) / 256;          // 51,200 one-shot blocks
        // K1_a (R16 verbatim) then K1_b (writes identical bits; its duration
        // = dur_us - 97.6). K2 reads whichever bits (identical by math).
        lif_walk<<<grid1, ROWS, 0, stream>>>(x, (uint4*)d_ws, n_rows);
        lif_walk_b<<<grid1, ROWS, 0, stream>>>(x, (uint4*)d_ws, n_rows);
        lif_expand<<<grid2, 256, 0, stream>>>((const unsigned int*)d_ws,
                                              (vfloat4*)out, total_f4);
    } else {
        lif_kernel<<<grid1, ROWS, 0, stream>>>(x, out, n_rows);
    }
}

// Round 18
// 84.718 us; speedup vs baseline: 2.0690x; 2.0690x over previous
//
#include <hip/hip_runtime.h>
#include <stdint.h>

// LIF neuron scan: v = v*0.5 + x[t]; s = (v - 0.5 > 0); v -= s*0.5
// Round 17 -> 18: LAST UNTRIED READ MECHANISM - global_load_lds DMA.
// Falsified so far: spill (R10), read request rate (R11 helped, capped at
// 3.2 TB/s), occupancy (R13), kernel split (R14), persistent pipeline (R15),
// K2 shape (R16), MLP/lookahead (R17: K1_b = 77.7us, WORSE than K1_a).
// Invariant: read phase ~3.2 TB/s vs write phase ~7 TB/s. In-flight bytes
// were never short (156KB/CU >> 9.2KB needed) -> the cap is the read
// MECHANISM: every load round-trips HBM->L1->VGPR->ds_write->LDS.
// global_load_lds (guide Common-mistake #1, compiler never auto-emits)
// DMAs straight to LDS: no VGPR writeback, no ds_write instructions.
// Our staging is its exact sweet spot: linear LDS dest = wave-uniform base
// + lane*16 <- linear global stream, 25 x 1KB per wave.
// Bonus: linear stride-25-f4 LDS is bank-conflict-FLOOR for the b128 row
// walk (banks (4*lane+4c) mod 32: all 8 four-bank groups hit evenly, 8
// touches/bank = b128 minimum) -> no swizzle needed at all.
// Everything else identical to R11 (26.6KB LDS, 6 blocks/CU, bit-pack,
// proven expansion store) -> clean mechanism-only A/B vs 89.5us.

#define T_STEPS 100
#define T_VEC   25      // f4 per row
#define ROWS    64      // rows per block == blockDim.x (one wave)
#define DECAY   0.5f
#define VTH     0.5f

typedef float vfloat4 __attribute__((ext_vector_type(4)));

__device__ __forceinline__ void gll16(const vfloat4* g, vfloat4* l) {
    // 16B-per-lane DMA: LDS dest = (uniform) l + lane*16; global src per-lane.
    __builtin_amdgcn_global_load_lds(
        (const __attribute__((address_space(1))) void*)g,
        (__attribute__((address_space(3))) void*)l,
        16, 0, 0);
}

__global__ __launch_bounds__(64) void lif_gll(const float* __restrict__ x,
                                              float* __restrict__ out,
                                              int n_rows) {
    __shared__ vfloat4 tile[ROWS * T_VEC];   // 25,600 B, linear [row][c]
    __shared__ uint4   bits[ROWS];           //  1,024 B -> 26,624 total

    const int lane = threadIdx.x;
    const int row0 = blockIdx.x * ROWS;
    const int gf0  = row0 * T_VEC;
    const int total_f4 = n_rows * T_VEC;

    const vfloat4* __restrict__ xb = reinterpret_cast<const vfloat4*>(x);

    unsigned int pk0 = 0, pk1 = 0, pk2 = 0, pk3 = 0;

    if (gf0 + ROWS * T_VEC <= total_f4) {
        // ---- DMA stage: 25 x global_load_lds_dwordx4, 1KB each, linear ----
        #pragma unroll
        for (int k = 0; k < T_VEC; ++k)
            gll16(xb + (gf0 + k * 64 + lane), &tile[k * 64]);

        // Compiler cannot see the DMA->LDS dependency: explicit drain, then
        // pin so no ds_read is hoisted above it (rule #18 discipline).
        asm volatile("s_waitcnt vmcnt(0)" ::: "memory");
        __builtin_amdgcn_sched_barrier(0);

        // ---- Walk own row: 25 x ds_read_b128 at stride 25 f4 (bank floor),
        //      100-step serial LIF, spikes packed to 4 u32 ----
        float v = 0.0f;
        #pragma unroll
        for (int c = 0; c < T_VEC; ++c) {
            vfloat4 xs = tile[lane * T_VEC + c];
            #pragma unroll
            for (int k = 0; k < 4; ++k) {
                // v*0.5 exact (pow2); conditional -0.5 exact -> bitwise == ref.
                v = v * DECAY + xs[k];
                bool sp = (v - VTH > 0.0f);
                v -= sp ? VTH : 0.0f;
                unsigned int bit = sp ? 1u : 0u;
                const int b = c * 4 + k;             // compile-time 0..99
                if      (b < 32) pk0 |= bit << b;
                else if (b < 64) pk1 |= bit << (b - 32);
                else if (b < 96) pk2 |= bit << (b - 64);
                else             pk3 |= bit << (b - 96);
            }
        }
    } else {
        // Tail blocks (not hit at this shape: 524288 % 64 == 0): direct
        // per-lane strided loads, same math.
        if (row0 + lane < n_rows) {
            const vfloat4* __restrict__ xr =
                xb + (long long)(row0 + lane) * T_VEC;
            float v = 0.0f;
            #pragma unroll
            for (int c = 0; c < T_VEC; ++c) {
                vfloat4 xs = xr[c];
                #pragma unroll
                for (int k = 0; k < 4; ++k) {
                    v = v * DECAY + xs[k];
                    bool sp = (v - VTH > 0.0f);
                    v -= sp ? VTH : 0.0f;
                    unsigned int bit = sp ? 1u : 0u;
                    const int b = c * 4 + k;
                    if      (b < 32) pk0 |= bit << b;
                    else if (b < 64) pk1 |= bit << (b - 32);
                    else if (b < 96) pk2 |= bit << (b - 64);
                    else             pk3 |= bit << (b - 96);
                }
            }
        }
    }

    // ---- Bits to LDS, one barrier, expansion (R10/R11 proven path) ----
    {
        uint4 w; w.x = pk0; w.y = pk1; w.z = pk2; w.w = pk3;
        bits[lane] = w;
    }
    __syncthreads();

    vfloat4* __restrict__ ob = reinterpret_cast<vfloat4*>(out);
    const unsigned int* bw = reinterpret_cast<const unsigned int*>(bits);
    #pragma unroll
    for (int i = 0; i < T_VEC; ++i) {
        int f = i * 64 + lane;                       // 0..1599
        int g = gf0 + f;
        if (g < total_f4) {
            int r  = f / T_VEC;                      // magic-mul
            int c4 = f % T_VEC;
            unsigned int word = bw[r * 4 + (c4 >> 3)];   // broadcast-heavy
            unsigned int nib = (word >> ((c4 & 7) * 4)) & 0xFu;
            vfloat4 s;
            s.x = (nib & 1u) ? 1.0f : 0.0f;
            s.y = (nib & 2u) ? 1.0f : 0.0f;
            s.z = (nib & 4u) ? 1.0f : 0.0f;
            s.w = (nib & 8u) ? 1.0f : 0.0f;
            ob[g] = s;
        }
    }
}

extern "C" void kernel_launch(void* const* d_in, const int* in_sizes, int n_in,
                              void* d_out, int out_size, void* d_ws, size_t ws_size,
                              hipStream_t stream) {
    const float* x = (const float*)d_in[0];
    float* out = (float*)d_out;

    int n_rows = in_sizes[0] / T_STEPS;              // 32 * 16384 = 524288
    int grid = (n_rows + ROWS - 1) / ROWS;           // 8192

    lif_gll<<<grid, ROWS, 0, stream>>>(x, out, n_rows);
}